// Round 1
// baseline (343.008 us; speedup 1.0000x reference)
//
#include <hip/hip_runtime.h>
#include <hip/hip_bf16.h>

// Problem constants (setup_inputs: B=8, N=2048, D=768, fp32)
static constexpr int BB = 8;
static constexpr int NN = 2048;
static constexpr int DD = 768;

typedef __attribute__((ext_vector_type(8))) __bf16 bf16x8;
typedef __attribute__((ext_vector_type(4))) float f32x4;

__device__ __forceinline__ void gload_lds16(const __hip_bfloat16* g, __hip_bfloat16* l) {
  __builtin_amdgcn_global_load_lds(
      (const __attribute__((address_space(1))) void*)g,
      (__attribute__((address_space(3))) void*)l,
      16, 0, 0);
}

// ---------------- zero l/conf ----------------
__global__ void zero_kernel(float* __restrict__ p, int n) {
  int i = blockIdx.x * blockDim.x + threadIdx.x;
  if (i < n) p[i] = 0.f;
}

// ---------------- normalize mid -> Qn bf16 ----------------
// one wave per row of 768; 4 rows per 256-thread block
__global__ void normalize_kernel(const float* __restrict__ mid, __hip_bfloat16* __restrict__ Qn) {
  const int wave = threadIdx.x >> 6;
  const int lane = threadIdx.x & 63;
  const size_t row = (size_t)blockIdx.x * 4 + wave;
  const float* src = mid + row * DD;

  float4 v[3];
  float ss = 0.f;
#pragma unroll
  for (int j = 0; j < 3; ++j) {
    v[j] = *(const float4*)(src + j * 256 + lane * 4);
    ss += v[j].x * v[j].x + v[j].y * v[j].y + v[j].z * v[j].z + v[j].w * v[j].w;
  }
#pragma unroll
  for (int o = 32; o; o >>= 1) ss += __shfl_xor(ss, o, 64);
  const float inv = 1.0f / fmaxf(sqrtf(ss), 1e-12f);

  __hip_bfloat16* dst = Qn + row * DD;
#pragma unroll
  for (int j = 0; j < 3; ++j) {
    union { ushort4 u; __hip_bfloat16 h[4]; } pk;
    pk.h[0] = __float2bfloat16(v[j].x * inv);
    pk.h[1] = __float2bfloat16(v[j].y * inv);
    pk.h[2] = __float2bfloat16(v[j].z * inv);
    pk.h[3] = __float2bfloat16(v[j].w * inv);
    *(ushort4*)(dst + j * 256 + lane * 4) = pk.u;
  }
}

// ---------------- transpose final (B,N,D) fp32 -> Vt (B,D,N) bf16 ----------------
__global__ void transpose_kernel(const float* __restrict__ F, __hip_bfloat16* __restrict__ Vt) {
  __shared__ __hip_bfloat16 tile[32][33];
  const int b = blockIdx.z;
  const int n0 = blockIdx.y * 32;
  const int d0 = blockIdx.x * 32;
  const int tx = threadIdx.x, ty = threadIdx.y;
#pragma unroll
  for (int i = 0; i < 4; ++i) {
    const int n = n0 + ty + i * 8;
    tile[ty + i * 8][tx] = __float2bfloat16(F[((size_t)b * NN + n) * DD + d0 + tx]);
  }
  __syncthreads();
#pragma unroll
  for (int i = 0; i < 4; ++i) {
    const int d = d0 + ty + i * 8;
    Vt[((size_t)b * DD + d) * NN + n0 + tx] = tile[tx][ty + i * 8];
  }
}

// ---------------- GEMM1: S = Qn·Qnᵀ per batch; epilogue exp / rowsum / rowmax / store P bf16 ----------------
__global__ __launch_bounds__(256) void gemm_qk_kernel(
    const __hip_bfloat16* __restrict__ Qn,
    __hip_bfloat16* __restrict__ P,
    float* __restrict__ lsum,
    unsigned* __restrict__ conf) {
  __shared__ __hip_bfloat16 smem[2 * 128 * 64];
  __hip_bfloat16* As = smem;
  __hip_bfloat16* Bs = smem + 128 * 64;

  const int b = blockIdx.z;
  const int rowBase = blockIdx.y * 128;
  const int colBase = blockIdx.x * 128;
  const int t = threadIdx.x;
  const int lane = t & 63;
  const int wave = t >> 6;
  const int wRow = wave >> 1;
  const int wCol = wave & 1;
  const int quad = lane >> 4;
  const int l16 = lane & 15;

  const __hip_bfloat16* Abase = Qn + ((size_t)b * NN + rowBase) * DD;
  const __hip_bfloat16* Bbase = Qn + ((size_t)b * NN + colBase) * DD;

  f32x4 acc[4][4];
#pragma unroll
  for (int i = 0; i < 4; ++i)
#pragma unroll
    for (int j = 0; j < 4; ++j) acc[i][j] = (f32x4){0.f, 0.f, 0.f, 0.f};

  for (int k0 = 0; k0 < DD; k0 += 64) {
    __syncthreads();
#pragma unroll
    for (int i = 0; i < 4; ++i) {
      const int c = i * 256 + t;          // 1024 chunks of 16B per 128x64 tile
      const int row = c >> 3;
      const int col = (c & 7) * 8;
      gload_lds16(Abase + (size_t)row * DD + (k0 + col), As + c * 8);
      gload_lds16(Bbase + (size_t)row * DD + (k0 + col), Bs + c * 8);
    }
    __syncthreads();
#pragma unroll
    for (int ks = 0; ks < 2; ++ks) {
      bf16x8 af[4], bfr[4];
#pragma unroll
      for (int i = 0; i < 4; ++i) {
        af[i]  = *(const bf16x8*)(As + (wRow * 64 + i * 16 + l16) * 64 + ks * 32 + quad * 8);
        bfr[i] = *(const bf16x8*)(Bs + (wCol * 64 + i * 16 + l16) * 64 + ks * 32 + quad * 8);
      }
#pragma unroll
      for (int mi = 0; mi < 4; ++mi)
#pragma unroll
        for (int ni = 0; ni < 4; ++ni)
          acc[mi][ni] = __builtin_amdgcn_mfma_f32_16x16x32_bf16(af[mi], bfr[ni], acc[mi][ni], 0, 0, 0);
    }
  }

  __syncthreads();  // all LDS reads done; reuse smem as P tile
  __hip_bfloat16* Pt = smem;  // [128][128] bf16 = 32 KB

#pragma unroll
  for (int mi = 0; mi < 4; ++mi) {
#pragma unroll
    for (int r = 0; r < 4; ++r) {
      const int rowL = wRow * 64 + mi * 16 + quad * 4 + r;
      const int row_g = rowBase + rowL;
      float ps = 0.f;
      float mx = 0.f;  // clamped at 0: valid since diag contributes sim=0 to the true max
#pragma unroll
      for (int ni = 0; ni < 4; ++ni) {
        const int colL = wCol * 64 + ni * 16 + l16;
        const int col_g = colBase + colL;
        float s = acc[mi][ni][r];
        if (row_g == col_g) s = 0.f;   // zeroed diagonal
        const float p = __expf(s);     // T=1; no max-subtraction needed, |s|<=1
        mx = fmaxf(mx, s);
        ps += p;
        Pt[rowL * 128 + colL] = __float2bfloat16(p);
      }
#pragma unroll
      for (int o = 1; o < 16; o <<= 1) {
        ps += __shfl_xor(ps, o, 64);
        mx = fmaxf(mx, __shfl_xor(mx, o, 64));
      }
      if (l16 == 0) {
        atomicAdd(lsum + (size_t)b * NN + row_g, ps);
        atomicMax(conf + (size_t)b * NN + row_g, __float_as_uint(mx));  // nonneg floats: uint order == float order
      }
    }
  }
  __syncthreads();
  const size_t pBase = ((size_t)b * NN + rowBase) * (size_t)NN + colBase;
#pragma unroll
  for (int i = 0; i < 8; ++i) {
    const int c = i * 256 + t;  // 2048 chunks of 16B
    const int row = c >> 4;
    const int col = (c & 15) * 8;
    *(uint4*)(P + pBase + (size_t)row * NN + col) = *(const uint4*)(Pt + row * 128 + col);
  }
}

// ---------------- GEMM2: O = P·V, epilogue normalize + confidence blend ----------------
__global__ __launch_bounds__(256) void gemm_pv_kernel(
    const __hip_bfloat16* __restrict__ P,    // [B][N][N]
    const __hip_bfloat16* __restrict__ Vt,   // [B][D][N]
    const float* __restrict__ lsum,
    const float* __restrict__ conf,
    const float* __restrict__ F,             // [B][N][D] fp32
    float* __restrict__ Out) {
  __shared__ __hip_bfloat16 smem[2 * 128 * 64];
  __hip_bfloat16* As = smem;
  __hip_bfloat16* Bs = smem + 128 * 64;

  const int b = blockIdx.z;
  const int rowBase = blockIdx.y * 128;   // over N
  const int colBase = blockIdx.x * 128;   // over D
  const int t = threadIdx.x;
  const int lane = t & 63;
  const int wave = t >> 6;
  const int wRow = wave >> 1;
  const int wCol = wave & 1;
  const int quad = lane >> 4;
  const int l16 = lane & 15;

  const __hip_bfloat16* Abase = P + (size_t)b * NN * NN + (size_t)rowBase * NN;
  const __hip_bfloat16* Bbase = Vt + (size_t)b * DD * NN + (size_t)colBase * NN;

  f32x4 acc[4][4];
#pragma unroll
  for (int i = 0; i < 4; ++i)
#pragma unroll
    for (int j = 0; j < 4; ++j) acc[i][j] = (f32x4){0.f, 0.f, 0.f, 0.f};

  for (int k0 = 0; k0 < NN; k0 += 64) {
    __syncthreads();
#pragma unroll
    for (int i = 0; i < 4; ++i) {
      const int c = i * 256 + t;
      const int row = c >> 3;
      const int col = (c & 7) * 8;
      gload_lds16(Abase + (size_t)row * NN + (k0 + col), As + c * 8);
      gload_lds16(Bbase + (size_t)row * NN + (k0 + col), Bs + c * 8);
    }
    __syncthreads();
#pragma unroll
    for (int ks = 0; ks < 2; ++ks) {
      bf16x8 af[4], bfr[4];
#pragma unroll
      for (int i = 0; i < 4; ++i) {
        af[i]  = *(const bf16x8*)(As + (wRow * 64 + i * 16 + l16) * 64 + ks * 32 + quad * 8);
        bfr[i] = *(const bf16x8*)(Bs + (wCol * 64 + i * 16 + l16) * 64 + ks * 32 + quad * 8);
      }
#pragma unroll
      for (int mi = 0; mi < 4; ++mi)
#pragma unroll
        for (int ni = 0; ni < 4; ++ni)
          acc[mi][ni] = __builtin_amdgcn_mfma_f32_16x16x32_bf16(af[mi], bfr[ni], acc[mi][ni], 0, 0, 0);
    }
  }

#pragma unroll
  for (int mi = 0; mi < 4; ++mi) {
#pragma unroll
    for (int r = 0; r < 4; ++r) {
      const int row_g = rowBase + wRow * 64 + mi * 16 + quad * 4 + r;
      const float li = lsum[(size_t)b * NN + row_g];
      const float cw = conf[(size_t)b * NN + row_g];
      const float inv = 1.0f / li;   // li >= 1 (diag contributes exp(0)=1)
      const float* frow = F + ((size_t)b * NN + row_g) * DD;
      float* orow = Out + ((size_t)b * NN + row_g) * DD;
#pragma unroll
      for (int ni = 0; ni < 4; ++ni) {
        const int col_g = colBase + wCol * 64 + ni * 16 + l16;
        const float o = acc[mi][ni][r] * inv;
        orow[col_g] = cw * o + (1.f - cw) * frow[col_g];
      }
    }
  }
}

extern "C" void kernel_launch(void* const* d_in, const int* in_sizes, int n_in,
                              void* d_out, int out_size, void* d_ws, size_t ws_size,
                              hipStream_t stream) {
  const float* F = (const float*)d_in[0];   // final_features
  const float* M = (const float*)d_in[1];   // mid_features
  float* Out = (float*)d_out;

  char* ws = (char*)d_ws;
  // layout: Qn (25165824) | Vt (25165824) | P (67108864) | lsum (65536) | conf (65536)
  __hip_bfloat16* Qn = (__hip_bfloat16*)(ws);
  __hip_bfloat16* Vt = (__hip_bfloat16*)(ws + 25165824);
  __hip_bfloat16* P  = (__hip_bfloat16*)(ws + 50331648);
  float* lsum        = (float*)(ws + 117440512);
  float* conf        = (float*)(ws + 117506048);

  zero_kernel<<<128, 256, 0, stream>>>(lsum, 2 * BB * NN);  // lsum + conf contiguous
  normalize_kernel<<<(BB * NN) / 4, 256, 0, stream>>>(M, Qn);
  transpose_kernel<<<dim3(DD / 32, NN / 32, BB), dim3(32, 8), 0, stream>>>(F, Vt);
  gemm_qk_kernel<<<dim3(NN / 128, NN / 128, BB), 256, 0, stream>>>(Qn, P, lsum, (unsigned*)conf);
  gemm_pv_kernel<<<dim3(DD / 128, NN / 128, BB), 256, 0, stream>>>(P, Vt, lsum, conf, F, Out);
}

// Round 2
// 324.998 us; speedup vs baseline: 1.0554x; 1.0554x over previous
//
#include <hip/hip_runtime.h>
#include <hip/hip_bf16.h>

// Problem constants (setup_inputs: B=8, N=2048, D=768, fp32)
static constexpr int BB = 8;
static constexpr int NN = 2048;
static constexpr int DD = 768;

typedef __attribute__((ext_vector_type(8))) __bf16 bf16x8;
typedef __attribute__((ext_vector_type(4))) float f32x4;

__device__ __forceinline__ void gload_lds16(const __hip_bfloat16* g, __hip_bfloat16* l) {
  __builtin_amdgcn_global_load_lds(
      (const __attribute__((address_space(1))) void*)g,
      (__attribute__((address_space(3))) void*)l,
      16, 0, 0);
}

// ---------------- normalize mid -> Qn bf16 ; also zero lsum/conf ----------------
// one wave per row of 768; 4 rows per 256-thread block
__global__ void normalize_kernel(const float* __restrict__ mid, __hip_bfloat16* __restrict__ Qn,
                                 float* __restrict__ lsum, float* __restrict__ conf) {
  const int wave = threadIdx.x >> 6;
  const int lane = threadIdx.x & 63;
  const size_t row = (size_t)blockIdx.x * 4 + wave;
  if (lane == 0) { lsum[row] = 0.f; conf[row] = 0.f; }
  const float* src = mid + row * DD;

  float4 v[3];
  float ss = 0.f;
#pragma unroll
  for (int j = 0; j < 3; ++j) {
    v[j] = *(const float4*)(src + j * 256 + lane * 4);
    ss += v[j].x * v[j].x + v[j].y * v[j].y + v[j].z * v[j].z + v[j].w * v[j].w;
  }
#pragma unroll
  for (int o = 32; o; o >>= 1) ss += __shfl_xor(ss, o, 64);
  const float inv = 1.0f / fmaxf(sqrtf(ss), 1e-12f);

  __hip_bfloat16* dst = Qn + row * DD;
#pragma unroll
  for (int j = 0; j < 3; ++j) {
    union { ushort4 u; __hip_bfloat16 h[4]; } pk;
    pk.h[0] = __float2bfloat16(v[j].x * inv);
    pk.h[1] = __float2bfloat16(v[j].y * inv);
    pk.h[2] = __float2bfloat16(v[j].z * inv);
    pk.h[3] = __float2bfloat16(v[j].w * inv);
    *(ushort4*)(dst + j * 256 + lane * 4) = pk.u;
  }
}

// ---------------- transpose final (B,N,D) fp32 -> Vt (B,D,N) bf16 ----------------
__global__ void transpose_kernel(const float* __restrict__ F, __hip_bfloat16* __restrict__ Vt) {
  __shared__ __hip_bfloat16 tile[32][33];
  const int b = blockIdx.z;
  const int n0 = blockIdx.y * 32;
  const int d0 = blockIdx.x * 32;
  const int tx = threadIdx.x, ty = threadIdx.y;
#pragma unroll
  for (int i = 0; i < 4; ++i) {
    const int n = n0 + ty + i * 8;
    tile[ty + i * 8][tx] = __float2bfloat16(F[((size_t)b * NN + n) * DD + d0 + tx]);
  }
  __syncthreads();
#pragma unroll
  for (int i = 0; i < 4; ++i) {
    const int d = d0 + ty + i * 8;
    Vt[((size_t)b * DD + d) * NN + n0 + tx] = tile[tx][ty + i * 8];
  }
}

// ---------------- GEMM1: S = Qn·Qnᵀ per batch; epilogue exp / rowsum / rowmax / store P bf16 ----------------
// 1D grid, XCD-aware remap: xcd k <- batch k (Qn batch = 3 MB fits one XCD L2)
__global__ __launch_bounds__(256) void gemm_qk_kernel(
    const __hip_bfloat16* __restrict__ Qn,
    __hip_bfloat16* __restrict__ P,
    float* __restrict__ lsum,
    unsigned* __restrict__ conf) {
  __shared__ __hip_bfloat16 smem[2 * 128 * 64];
  __hip_bfloat16* As = smem;
  __hip_bfloat16* Bs = smem + 128 * 64;

  const int d = blockIdx.x;                 // 0..2047
  const int work = (d & 7) * 256 + (d >> 3);
  const int colBase = (work & 15) * 128;
  const int rowBase = ((work >> 4) & 15) * 128;
  const int b = work >> 8;

  const int t = threadIdx.x;
  const int lane = t & 63;
  const int wave = t >> 6;
  const int wRow = wave >> 1;
  const int wCol = wave & 1;
  const int quad = lane >> 4;
  const int l16 = lane & 15;

  const __hip_bfloat16* Abase = Qn + ((size_t)b * NN + rowBase) * DD;
  const __hip_bfloat16* Bbase = Qn + ((size_t)b * NN + colBase) * DD;

  f32x4 acc[4][4];
#pragma unroll
  for (int i = 0; i < 4; ++i)
#pragma unroll
    for (int j = 0; j < 4; ++j) acc[i][j] = (f32x4){0.f, 0.f, 0.f, 0.f};

  for (int k0 = 0; k0 < DD; k0 += 64) {
    __syncthreads();
#pragma unroll
    for (int i = 0; i < 4; ++i) {
      const int c = i * 256 + t;            // LDS chunk slot (lane-contiguous for global_load_lds)
      const int row = c >> 3;
      const int col8 = (c & 7) ^ (row & 7); // XOR-swizzle: which global chunk lands in this slot
      gload_lds16(Abase + (size_t)row * DD + (k0 + col8 * 8), As + c * 8);
      gload_lds16(Bbase + (size_t)row * DD + (k0 + col8 * 8), Bs + c * 8);
    }
    __syncthreads();
#pragma unroll
    for (int ks = 0; ks < 2; ++ks) {
      bf16x8 af[4], bfr[4];
#pragma unroll
      for (int i = 0; i < 4; ++i) {
        const int rA = wRow * 64 + i * 16 + l16;
        const int rB = wCol * 64 + i * 16 + l16;
        const int pA = (ks * 4 + quad) ^ (rA & 7);
        const int pB = (ks * 4 + quad) ^ (rB & 7);
        af[i]  = *(const bf16x8*)(As + rA * 64 + pA * 8);
        bfr[i] = *(const bf16x8*)(Bs + rB * 64 + pB * 8);
      }
#pragma unroll
      for (int mi = 0; mi < 4; ++mi)
#pragma unroll
        for (int ni = 0; ni < 4; ++ni)
          acc[mi][ni] = __builtin_amdgcn_mfma_f32_16x16x32_bf16(af[mi], bfr[ni], acc[mi][ni], 0, 0, 0);
    }
  }

  __syncthreads();  // all LDS reads done; reuse smem as P tile
  __hip_bfloat16* Pt = smem;  // [128][128] bf16 = 32 KB

#pragma unroll
  for (int mi = 0; mi < 4; ++mi) {
#pragma unroll
    for (int r = 0; r < 4; ++r) {
      const int rowL = wRow * 64 + mi * 16 + quad * 4 + r;
      const int row_g = rowBase + rowL;
      float ps = 0.f;
      float mx = 0.f;  // clamped at 0: valid since diag contributes sim=0 to the true max
#pragma unroll
      for (int ni = 0; ni < 4; ++ni) {
        const int colL = wCol * 64 + ni * 16 + l16;
        const int col_g = colBase + colL;
        float s = acc[mi][ni][r];
        if (row_g == col_g) s = 0.f;   // zeroed diagonal
        const float p = __expf(s);     // T=1; no max-subtraction needed, |s|<=1
        mx = fmaxf(mx, s);
        ps += p;
        Pt[rowL * 128 + colL] = __float2bfloat16(p);
      }
#pragma unroll
      for (int o = 1; o < 16; o <<= 1) {
        ps += __shfl_xor(ps, o, 64);
        mx = fmaxf(mx, __shfl_xor(mx, o, 64));
      }
      if (l16 == 0) {
        atomicAdd(lsum + (size_t)b * NN + row_g, ps);
        atomicMax(conf + (size_t)b * NN + row_g, __float_as_uint(mx));  // nonneg: uint order == float order
      }
    }
  }
  __syncthreads();
  const size_t pBase = ((size_t)b * NN + rowBase) * (size_t)NN + colBase;
#pragma unroll
  for (int i = 0; i < 8; ++i) {
    const int c = i * 256 + t;  // 2048 chunks of 16B
    const int row = c >> 4;
    const int col = (c & 15) * 8;
    *(uint4*)(P + pBase + (size_t)row * NN + col) = *(const uint4*)(Pt + row * 128 + col);
  }
}

// ---------------- GEMM2: O = P·V, epilogue normalize + confidence blend ----------------
// 1D grid, XCD-aware remap: xcd k <- batch k (Vt batch = 3 MB fits one XCD L2)
__global__ __launch_bounds__(256) void gemm_pv_kernel(
    const __hip_bfloat16* __restrict__ P,    // [B][N][N]
    const __hip_bfloat16* __restrict__ Vt,   // [B][D][N]
    const float* __restrict__ lsum,
    const float* __restrict__ conf,
    const float* __restrict__ F,             // [B][N][D] fp32
    float* __restrict__ Out) {
  __shared__ __hip_bfloat16 smem[2 * 128 * 64];
  __hip_bfloat16* As = smem;
  __hip_bfloat16* Bs = smem + 128 * 64;

  const int d = blockIdx.x;                 // 0..767
  const int work = (d & 7) * 96 + (d >> 3);
  const int colBase = (work % 6) * 128;     // over D
  const int rowBase = ((work / 6) & 15) * 128;  // over N
  const int b = work / 96;

  const int t = threadIdx.x;
  const int lane = t & 63;
  const int wave = t >> 6;
  const int wRow = wave >> 1;
  const int wCol = wave & 1;
  const int quad = lane >> 4;
  const int l16 = lane & 15;

  const __hip_bfloat16* Abase = P + (size_t)b * NN * NN + (size_t)rowBase * NN;
  const __hip_bfloat16* Bbase = Vt + (size_t)b * DD * NN + (size_t)colBase * NN;

  f32x4 acc[4][4];
#pragma unroll
  for (int i = 0; i < 4; ++i)
#pragma unroll
    for (int j = 0; j < 4; ++j) acc[i][j] = (f32x4){0.f, 0.f, 0.f, 0.f};

  for (int k0 = 0; k0 < NN; k0 += 64) {
    __syncthreads();
#pragma unroll
    for (int i = 0; i < 4; ++i) {
      const int c = i * 256 + t;
      const int row = c >> 3;
      const int col8 = (c & 7) ^ (row & 7);
      gload_lds16(Abase + (size_t)row * NN + (k0 + col8 * 8), As + c * 8);
      gload_lds16(Bbase + (size_t)row * NN + (k0 + col8 * 8), Bs + c * 8);
    }
    __syncthreads();
#pragma unroll
    for (int ks = 0; ks < 2; ++ks) {
      bf16x8 af[4], bfr[4];
#pragma unroll
      for (int i = 0; i < 4; ++i) {
        const int rA = wRow * 64 + i * 16 + l16;
        const int rB = wCol * 64 + i * 16 + l16;
        const int pA = (ks * 4 + quad) ^ (rA & 7);
        const int pB = (ks * 4 + quad) ^ (rB & 7);
        af[i]  = *(const bf16x8*)(As + rA * 64 + pA * 8);
        bfr[i] = *(const bf16x8*)(Bs + rB * 64 + pB * 8);
      }
#pragma unroll
      for (int mi = 0; mi < 4; ++mi)
#pragma unroll
        for (int ni = 0; ni < 4; ++ni)
          acc[mi][ni] = __builtin_amdgcn_mfma_f32_16x16x32_bf16(af[mi], bfr[ni], acc[mi][ni], 0, 0, 0);
    }
  }

#pragma unroll
  for (int mi = 0; mi < 4; ++mi) {
#pragma unroll
    for (int r = 0; r < 4; ++r) {
      const int row_g = rowBase + wRow * 64 + mi * 16 + quad * 4 + r;
      const float li = lsum[(size_t)b * NN + row_g];
      const float cw = conf[(size_t)b * NN + row_g];
      const float inv = 1.0f / li;   // li >= 1 (diag contributes exp(0)=1)
      const float* frow = F + ((size_t)b * NN + row_g) * DD;
      float* orow = Out + ((size_t)b * NN + row_g) * DD;
#pragma unroll
      for (int ni = 0; ni < 4; ++ni) {
        const int col_g = colBase + wCol * 64 + ni * 16 + l16;
        const float o = acc[mi][ni][r] * inv;
        orow[col_g] = cw * o + (1.f - cw) * frow[col_g];
      }
    }
  }
}

extern "C" void kernel_launch(void* const* d_in, const int* in_sizes, int n_in,
                              void* d_out, int out_size, void* d_ws, size_t ws_size,
                              hipStream_t stream) {
  const float* F = (const float*)d_in[0];   // final_features
  const float* M = (const float*)d_in[1];   // mid_features
  float* Out = (float*)d_out;

  char* ws = (char*)d_ws;
  // layout: Qn (25165824) | Vt (25165824) | P (67108864) | lsum (65536) | conf (65536)
  __hip_bfloat16* Qn = (__hip_bfloat16*)(ws);
  __hip_bfloat16* Vt = (__hip_bfloat16*)(ws + 25165824);
  __hip_bfloat16* P  = (__hip_bfloat16*)(ws + 50331648);
  float* lsum        = (float*)(ws + 117440512);
  float* conf        = (float*)(ws + 117506048);

  normalize_kernel<<<(BB * NN) / 4, 256, 0, stream>>>(M, Qn, lsum, conf);
  transpose_kernel<<<dim3(DD / 32, NN / 32, BB), dim3(32, 8), 0, stream>>>(F, Vt);
  gemm_qk_kernel<<<2048, 256, 0, stream>>>(Qn, P, lsum, (unsigned*)conf);
  gemm_pv_kernel<<<768, 256, 0, stream>>>(P, Vt, lsum, conf, F, Out);
}

// Round 3
// 319.339 us; speedup vs baseline: 1.0741x; 1.0177x over previous
//
#include <hip/hip_runtime.h>
#include <hip/hip_bf16.h>

// Problem constants (setup_inputs: B=8, N=2048, D=768, fp32)
static constexpr int BB = 8;
static constexpr int NN = 2048;
static constexpr int DD = 768;

typedef __attribute__((ext_vector_type(8))) __bf16 bf16x8;
typedef __attribute__((ext_vector_type(4))) float f32x4;

__device__ __forceinline__ void gload_lds16(const __hip_bfloat16* g, __hip_bfloat16* l) {
  __builtin_amdgcn_global_load_lds(
      (const __attribute__((address_space(1))) void*)g,
      (__attribute__((address_space(3))) void*)l,
      16, 0, 0);
}

// ---------------- normalize mid -> Qn bf16 ; also zero lsum/conf ----------------
__global__ void normalize_kernel(const float* __restrict__ mid, __hip_bfloat16* __restrict__ Qn,
                                 float* __restrict__ lsum, float* __restrict__ conf) {
  const int wave = threadIdx.x >> 6;
  const int lane = threadIdx.x & 63;
  const size_t row = (size_t)blockIdx.x * 4 + wave;
  if (lane == 0) { lsum[row] = 0.f; conf[row] = 0.f; }
  const float* src = mid + row * DD;

  float4 v[3];
  float ss = 0.f;
#pragma unroll
  for (int j = 0; j < 3; ++j) {
    v[j] = *(const float4*)(src + j * 256 + lane * 4);
    ss += v[j].x * v[j].x + v[j].y * v[j].y + v[j].z * v[j].z + v[j].w * v[j].w;
  }
#pragma unroll
  for (int o = 32; o; o >>= 1) ss += __shfl_xor(ss, o, 64);
  const float inv = 1.0f / fmaxf(sqrtf(ss), 1e-12f);

  __hip_bfloat16* dst = Qn + row * DD;
#pragma unroll
  for (int j = 0; j < 3; ++j) {
    union { ushort4 u; __hip_bfloat16 h[4]; } pk;
    pk.h[0] = __float2bfloat16(v[j].x * inv);
    pk.h[1] = __float2bfloat16(v[j].y * inv);
    pk.h[2] = __float2bfloat16(v[j].z * inv);
    pk.h[3] = __float2bfloat16(v[j].w * inv);
    *(ushort4*)(dst + j * 256 + lane * 4) = pk.u;
  }
}

// ---------------- transpose final (B,N,D) fp32 -> Vt (B,D,N) bf16 ----------------
__global__ void transpose_kernel(const float* __restrict__ F, __hip_bfloat16* __restrict__ Vt) {
  __shared__ __hip_bfloat16 tile[32][33];
  const int b = blockIdx.z;
  const int n0 = blockIdx.y * 32;
  const int d0 = blockIdx.x * 32;
  const int tx = threadIdx.x, ty = threadIdx.y;
#pragma unroll
  for (int i = 0; i < 4; ++i) {
    const int n = n0 + ty + i * 8;
    tile[ty + i * 8][tx] = __float2bfloat16(F[((size_t)b * NN + n) * DD + d0 + tx]);
  }
  __syncthreads();
#pragma unroll
  for (int i = 0; i < 4; ++i) {
    const int d = d0 + ty + i * 8;
    Vt[((size_t)b * DD + d) * NN + n0 + tx] = tile[tx][ty + i * 8];
  }
}

// ---------------- GEMM1: S = Qn·Qnᵀ ; pipelined dbuf LDS; epilogue exp/rowsum/rowmax/P ----------------
__global__ __launch_bounds__(256) void gemm_qk_kernel(
    const __hip_bfloat16* __restrict__ Qn,
    __hip_bfloat16* __restrict__ P,
    float* __restrict__ lsum,
    unsigned* __restrict__ conf) {
  __shared__ __hip_bfloat16 smem[4 * 128 * 64];  // 64 KB: [buf][A|B][128][64]

  const int d = blockIdx.x;                 // 0..2047
  const int work = (d & 7) * 256 + (d >> 3);  // XCD k <- batch k (Qn batch 3 MB fits XCD L2)
  const int colBase = (work & 15) * 128;
  const int rowBase = ((work >> 4) & 15) * 128;
  const int b = work >> 8;

  const int t = threadIdx.x;
  const int lane = t & 63;
  const int wave = t >> 6;
  const int wRow = wave >> 1;
  const int wCol = wave & 1;
  const int quad = lane >> 4;
  const int l16 = lane & 15;

  const __hip_bfloat16* Abase = Qn + ((size_t)b * NN + rowBase) * DD;
  const __hip_bfloat16* Bbase = Qn + ((size_t)b * NN + colBase) * DD;

  // staging slots (lane-contiguous dest for global_load_lds; source XOR-swizzled)
  int srow[4], scol[4], sc8[4];
#pragma unroll
  for (int i = 0; i < 4; ++i) {
    const int c = i * 256 + t;
    srow[i] = c >> 3;
    const int col8 = (c & 7) ^ ((c >> 3) & 7);
    scol[i] = col8 * 8;
    sc8[i] = c * 8;
  }

  f32x4 acc[4][4];
#pragma unroll
  for (int i = 0; i < 4; ++i)
#pragma unroll
    for (int j = 0; j < 4; ++j) acc[i][j] = (f32x4){0.f, 0.f, 0.f, 0.f};

  // prologue: stage tile 0 into buf 0
  {
    __hip_bfloat16* As = smem;
    __hip_bfloat16* Bs = smem + 128 * 64;
#pragma unroll
    for (int i = 0; i < 4; ++i) {
      gload_lds16(Abase + (size_t)srow[i] * DD + scol[i], As + sc8[i]);
      gload_lds16(Bbase + (size_t)srow[i] * DD + scol[i], Bs + sc8[i]);
    }
  }

  constexpr int NK = DD / 64;  // 12
  for (int kk = 0; kk < NK; ++kk) {
    const int cur = kk & 1;
    __syncthreads();  // buf[cur] staged; buf[1-cur] fully consumed
    if (kk + 1 < NK) {
      __hip_bfloat16* As = smem + (1 - cur) * 2 * 128 * 64;
      __hip_bfloat16* Bs = As + 128 * 64;
      const int k0 = (kk + 1) * 64;
#pragma unroll
      for (int i = 0; i < 4; ++i) {
        gload_lds16(Abase + (size_t)srow[i] * DD + (k0 + scol[i]), As + sc8[i]);
        gload_lds16(Bbase + (size_t)srow[i] * DD + (k0 + scol[i]), Bs + sc8[i]);
      }
    }
    const __hip_bfloat16* As = smem + cur * 2 * 128 * 64;
    const __hip_bfloat16* Bs = As + 128 * 64;
#pragma unroll
    for (int ks = 0; ks < 2; ++ks) {
      bf16x8 af[4], bfr[4];
#pragma unroll
      for (int i = 0; i < 4; ++i) {
        const int rA = wRow * 64 + i * 16 + l16;
        const int rB = wCol * 64 + i * 16 + l16;
        const int pA = (ks * 4 + quad) ^ (rA & 7);
        const int pB = (ks * 4 + quad) ^ (rB & 7);
        af[i]  = *(const bf16x8*)(As + rA * 64 + pA * 8);
        bfr[i] = *(const bf16x8*)(Bs + rB * 64 + pB * 8);
      }
#pragma unroll
      for (int mi = 0; mi < 4; ++mi)
#pragma unroll
        for (int ni = 0; ni < 4; ++ni)
          acc[mi][ni] = __builtin_amdgcn_mfma_f32_16x16x32_bf16(af[mi], bfr[ni], acc[mi][ni], 0, 0, 0);
    }
  }

  __syncthreads();  // all LDS reads done; reuse smem[0..32KB) as P tile
  __hip_bfloat16* Pt = smem;  // [128][128] bf16 = 32 KB

#pragma unroll
  for (int mi = 0; mi < 4; ++mi) {
#pragma unroll
    for (int r = 0; r < 4; ++r) {
      const int rowL = wRow * 64 + mi * 16 + quad * 4 + r;
      const int row_g = rowBase + rowL;
      float ps = 0.f;
      float mx = 0.f;  // clamp at 0 valid: diag contributes sim=0 to the true max
#pragma unroll
      for (int ni = 0; ni < 4; ++ni) {
        const int colL = wCol * 64 + ni * 16 + l16;
        const int col_g = colBase + colL;
        float s = acc[mi][ni][r];
        if (row_g == col_g) s = 0.f;   // zeroed diagonal
        const float p = __expf(s);     // T=1; |s|<=1 so no max-subtraction needed
        mx = fmaxf(mx, s);
        ps += p;
        Pt[rowL * 128 + colL] = __float2bfloat16(p);
      }
#pragma unroll
      for (int o = 1; o < 16; o <<= 1) {
        ps += __shfl_xor(ps, o, 64);
        mx = fmaxf(mx, __shfl_xor(mx, o, 64));
      }
      if (l16 == 0) {
        atomicAdd(lsum + (size_t)b * NN + row_g, ps);
        atomicMax(conf + (size_t)b * NN + row_g, __float_as_uint(mx));  // nonneg: uint order == float order
      }
    }
  }
  __syncthreads();
  const size_t pBase = ((size_t)b * NN + rowBase) * (size_t)NN + colBase;
#pragma unroll
  for (int i = 0; i < 8; ++i) {
    const int c = i * 256 + t;  // 2048 chunks of 16B
    const int row = c >> 4;
    const int col = (c & 15) * 8;
    *(uint4*)(P + pBase + (size_t)row * NN + col) = *(const uint4*)(Pt + row * 128 + col);
  }
}

// ---------------- GEMM2: O = P·V ; pipelined dbuf LDS; epilogue normalize + blend ----------------
__global__ __launch_bounds__(256) void gemm_pv_kernel(
    const __hip_bfloat16* __restrict__ P,    // [B][N][N]
    const __hip_bfloat16* __restrict__ Vt,   // [B][D][N]
    const float* __restrict__ lsum,
    const float* __restrict__ conf,
    const float* __restrict__ F,             // [B][N][D] fp32
    float* __restrict__ Out) {
  __shared__ __hip_bfloat16 smem[4 * 128 * 64];  // 64 KB

  const int d = blockIdx.x;                 // 0..767
  const int work = (d & 7) * 96 + (d >> 3);  // XCD k <- batch k (Vt batch 3 MB fits XCD L2)
  const int colBase = (work % 6) * 128;        // over D
  const int rowBase = ((work / 6) & 15) * 128; // over N
  const int b = work / 96;

  const int t = threadIdx.x;
  const int lane = t & 63;
  const int wave = t >> 6;
  const int wRow = wave >> 1;
  const int wCol = wave & 1;
  const int quad = lane >> 4;
  const int l16 = lane & 15;

  const __hip_bfloat16* Abase = P + (size_t)b * NN * NN + (size_t)rowBase * NN;
  const __hip_bfloat16* Bbase = Vt + (size_t)b * DD * NN + (size_t)colBase * NN;

  int srow[4], scol[4], sc8[4];
#pragma unroll
  for (int i = 0; i < 4; ++i) {
    const int c = i * 256 + t;
    srow[i] = c >> 3;
    const int col8 = (c & 7) ^ ((c >> 3) & 7);
    scol[i] = col8 * 8;
    sc8[i] = c * 8;
  }

  f32x4 acc[4][4];
#pragma unroll
  for (int i = 0; i < 4; ++i)
#pragma unroll
    for (int j = 0; j < 4; ++j) acc[i][j] = (f32x4){0.f, 0.f, 0.f, 0.f};

  {
    __hip_bfloat16* As = smem;
    __hip_bfloat16* Bs = smem + 128 * 64;
#pragma unroll
    for (int i = 0; i < 4; ++i) {
      gload_lds16(Abase + (size_t)srow[i] * NN + scol[i], As + sc8[i]);
      gload_lds16(Bbase + (size_t)srow[i] * NN + scol[i], Bs + sc8[i]);
    }
  }

  constexpr int NK = NN / 64;  // 32
  for (int kk = 0; kk < NK; ++kk) {
    const int cur = kk & 1;
    __syncthreads();
    if (kk + 1 < NK) {
      __hip_bfloat16* As = smem + (1 - cur) * 2 * 128 * 64;
      __hip_bfloat16* Bs = As + 128 * 64;
      const int k0 = (kk + 1) * 64;
#pragma unroll
      for (int i = 0; i < 4; ++i) {
        gload_lds16(Abase + (size_t)srow[i] * NN + (k0 + scol[i]), As + sc8[i]);
        gload_lds16(Bbase + (size_t)srow[i] * NN + (k0 + scol[i]), Bs + sc8[i]);
      }
    }
    const __hip_bfloat16* As = smem + cur * 2 * 128 * 64;
    const __hip_bfloat16* Bs = As + 128 * 64;
#pragma unroll
    for (int ks = 0; ks < 2; ++ks) {
      bf16x8 af[4], bfr[4];
#pragma unroll
      for (int i = 0; i < 4; ++i) {
        const int rA = wRow * 64 + i * 16 + l16;
        const int rB = wCol * 64 + i * 16 + l16;
        const int pA = (ks * 4 + quad) ^ (rA & 7);
        const int pB = (ks * 4 + quad) ^ (rB & 7);
        af[i]  = *(const bf16x8*)(As + rA * 64 + pA * 8);
        bfr[i] = *(const bf16x8*)(Bs + rB * 64 + pB * 8);
      }
#pragma unroll
      for (int mi = 0; mi < 4; ++mi)
#pragma unroll
        for (int ni = 0; ni < 4; ++ni)
          acc[mi][ni] = __builtin_amdgcn_mfma_f32_16x16x32_bf16(af[mi], bfr[ni], acc[mi][ni], 0, 0, 0);
    }
  }

#pragma unroll
  for (int mi = 0; mi < 4; ++mi) {
#pragma unroll
    for (int r = 0; r < 4; ++r) {
      const int row_g = rowBase + wRow * 64 + mi * 16 + quad * 4 + r;
      const float li = lsum[(size_t)b * NN + row_g];
      const float cw = conf[(size_t)b * NN + row_g];
      const float inv = 1.0f / li;   // li >= 1 (diag contributes exp(0)=1)
      const float* frow = F + ((size_t)b * NN + row_g) * DD;
      float* orow = Out + ((size_t)b * NN + row_g) * DD;
#pragma unroll
      for (int ni = 0; ni < 4; ++ni) {
        const int col_g = colBase + wCol * 64 + ni * 16 + l16;
        const float o = acc[mi][ni][r] * inv;
        orow[col_g] = cw * o + (1.f - cw) * frow[col_g];
      }
    }
  }
}

extern "C" void kernel_launch(void* const* d_in, const int* in_sizes, int n_in,
                              void* d_out, int out_size, void* d_ws, size_t ws_size,
                              hipStream_t stream) {
  const float* F = (const float*)d_in[0];   // final_features
  const float* M = (const float*)d_in[1];   // mid_features
  float* Out = (float*)d_out;

  char* ws = (char*)d_ws;
  // layout: Qn (25165824) | Vt (25165824) | P (67108864) | lsum (65536) | conf (65536)
  __hip_bfloat16* Qn = (__hip_bfloat16*)(ws);
  __hip_bfloat16* Vt = (__hip_bfloat16*)(ws + 25165824);
  __hip_bfloat16* P  = (__hip_bfloat16*)(ws + 50331648);
  float* lsum        = (float*)(ws + 117440512);
  float* conf        = (float*)(ws + 117506048);

  normalize_kernel<<<(BB * NN) / 4, 256, 0, stream>>>(M, Qn, lsum, conf);
  transpose_kernel<<<dim3(DD / 32, NN / 32, BB), dim3(32, 8), 0, stream>>>(F, Vt);
  gemm_qk_kernel<<<2048, 256, 0, stream>>>(Qn, P, lsum, (unsigned*)conf);
  gemm_pv_kernel<<<768, 256, 0, stream>>>(P, Vt, lsum, conf, F, Out);
}

// Round 4
// 291.168 us; speedup vs baseline: 1.1780x; 1.0968x over previous
//
#include <hip/hip_runtime.h>
#include <hip/hip_bf16.h>

// Problem constants (setup_inputs: B=8, N=2048, D=768, fp32)
static constexpr int BB = 8;
static constexpr int NN = 2048;
static constexpr int DD = 768;

typedef __attribute__((ext_vector_type(8))) __bf16 bf16x8;
typedef __attribute__((ext_vector_type(4))) float f32x4;

__device__ __forceinline__ void gload_lds16(const __hip_bfloat16* g, __hip_bfloat16* l) {
  __builtin_amdgcn_global_load_lds(
      (const __attribute__((address_space(1))) void*)g,
      (__attribute__((address_space(3))) void*)l,
      16, 0, 0);
}

// ---------------- normalize mid -> Qn bf16 ; also zero lsum/conf ----------------
__global__ void normalize_kernel(const float* __restrict__ mid, __hip_bfloat16* __restrict__ Qn,
                                 float* __restrict__ lsum, float* __restrict__ conf) {
  const int wave = threadIdx.x >> 6;
  const int lane = threadIdx.x & 63;
  const size_t row = (size_t)blockIdx.x * 4 + wave;
  if (lane == 0) { lsum[row] = 0.f; conf[row] = 0.f; }
  const float* src = mid + row * DD;

  float4 v[3];
  float ss = 0.f;
#pragma unroll
  for (int j = 0; j < 3; ++j) {
    v[j] = *(const float4*)(src + j * 256 + lane * 4);
    ss += v[j].x * v[j].x + v[j].y * v[j].y + v[j].z * v[j].z + v[j].w * v[j].w;
  }
#pragma unroll
  for (int o = 32; o; o >>= 1) ss += __shfl_xor(ss, o, 64);
  const float inv = 1.0f / fmaxf(sqrtf(ss), 1e-12f);

  __hip_bfloat16* dst = Qn + row * DD;
#pragma unroll
  for (int j = 0; j < 3; ++j) {
    union { ushort4 u; __hip_bfloat16 h[4]; } pk;
    pk.h[0] = __float2bfloat16(v[j].x * inv);
    pk.h[1] = __float2bfloat16(v[j].y * inv);
    pk.h[2] = __float2bfloat16(v[j].z * inv);
    pk.h[3] = __float2bfloat16(v[j].w * inv);
    *(ushort4*)(dst + j * 256 + lane * 4) = pk.u;
  }
}

// ---------------- transpose final (B,N,D) fp32 -> Vt (B,D,N) bf16 ----------------
__global__ void transpose_kernel(const float* __restrict__ F, __hip_bfloat16* __restrict__ Vt) {
  __shared__ __hip_bfloat16 tile[32][33];
  const int b = blockIdx.z;
  const int n0 = blockIdx.y * 32;
  const int d0 = blockIdx.x * 32;
  const int tx = threadIdx.x, ty = threadIdx.y;
#pragma unroll
  for (int i = 0; i < 4; ++i) {
    const int n = n0 + ty + i * 8;
    tile[ty + i * 8][tx] = __float2bfloat16(F[((size_t)b * NN + n) * DD + d0 + tx]);
  }
  __syncthreads();
#pragma unroll
  for (int i = 0; i < 4; ++i) {
    const int d = d0 + ty + i * 8;
    Vt[((size_t)b * DD + d) * NN + n0 + tx] = tile[tx][ty + i * 8];
  }
}

// ---------------- GEMM1 (symmetric): S = Qn·Qnᵀ, upper-triangle tiles only ----------------
// Off-diag tile (i,j), j>i: stores P[i,j] and P[j,i]^T; row stats -> stripe i, col stats -> stripe j.
// Pt padded to 136 halfs/row: 272 B rows (16B-aligned), bank stride 4.
static constexpr int PTL = 136;
__global__ __launch_bounds__(256) void gemm_qk_kernel(
    const __hip_bfloat16* __restrict__ Qn,
    __hip_bfloat16* __restrict__ P,
    float* __restrict__ lsum,
    unsigned* __restrict__ conf) {
  __shared__ __hip_bfloat16 smem[4 * 128 * 64];  // 64 KB: dbuf staging; epilogue reuses 34 KB as Pt

  const int d = blockIdx.x;                // 0..1087 (8 batches x 136 triangle tiles)
  const int b = d & 7;                     // XCD k <- batch k (Qn batch 3 MB fits XCD L2)
  int rem = d >> 3;                        // 0..135
  int ti = 0;
  while (rem >= 16 - ti) { rem -= 16 - ti; ++ti; }   // uniform scalar decode
  const int tj = ti + rem;                 // tj >= ti
  const int rowBase = ti * 128;
  const int colBase = tj * 128;
  const bool offdiag = (ti != tj);

  const int t = threadIdx.x;
  const int lane = t & 63;
  const int wave = t >> 6;
  const int wRow = wave >> 1;
  const int wCol = wave & 1;
  const int quad = lane >> 4;
  const int l16 = lane & 15;

  const __hip_bfloat16* Abase = Qn + ((size_t)b * NN + rowBase) * DD;
  const __hip_bfloat16* Bbase = Qn + ((size_t)b * NN + colBase) * DD;

  // staging slots (lane-contiguous dest for global_load_lds; source XOR-swizzled)
  int srow[4], scol[4], sc8[4];
#pragma unroll
  for (int i = 0; i < 4; ++i) {
    const int c = i * 256 + t;
    srow[i] = c >> 3;
    const int col8 = (c & 7) ^ ((c >> 3) & 7);
    scol[i] = col8 * 8;
    sc8[i] = c * 8;
  }

  f32x4 acc[4][4];
#pragma unroll
  for (int i = 0; i < 4; ++i)
#pragma unroll
    for (int j = 0; j < 4; ++j) acc[i][j] = (f32x4){0.f, 0.f, 0.f, 0.f};

  // prologue: stage tile 0 into buf 0
  {
    __hip_bfloat16* As = smem;
    __hip_bfloat16* Bs = smem + 128 * 64;
#pragma unroll
    for (int i = 0; i < 4; ++i) {
      gload_lds16(Abase + (size_t)srow[i] * DD + scol[i], As + sc8[i]);
      gload_lds16(Bbase + (size_t)srow[i] * DD + scol[i], Bs + sc8[i]);
    }
  }

  constexpr int NK = DD / 64;  // 12
  for (int kk = 0; kk < NK; ++kk) {
    const int cur = kk & 1;
    __syncthreads();  // buf[cur] staged; buf[1-cur] consumed
    if (kk + 1 < NK) {
      __hip_bfloat16* As = smem + (1 - cur) * 2 * 128 * 64;
      __hip_bfloat16* Bs = As + 128 * 64;
      const int k0 = (kk + 1) * 64;
#pragma unroll
      for (int i = 0; i < 4; ++i) {
        gload_lds16(Abase + (size_t)srow[i] * DD + (k0 + scol[i]), As + sc8[i]);
        gload_lds16(Bbase + (size_t)srow[i] * DD + (k0 + scol[i]), Bs + sc8[i]);
      }
    }
    const __hip_bfloat16* As = smem + cur * 2 * 128 * 64;
    const __hip_bfloat16* Bs = As + 128 * 64;
#pragma unroll
    for (int ks = 0; ks < 2; ++ks) {
      bf16x8 af[4], bfr[4];
#pragma unroll
      for (int i = 0; i < 4; ++i) {
        const int rA = wRow * 64 + i * 16 + l16;
        const int rB = wCol * 64 + i * 16 + l16;
        const int pA = (ks * 4 + quad) ^ (rA & 7);
        const int pB = (ks * 4 + quad) ^ (rB & 7);
        af[i]  = *(const bf16x8*)(As + rA * 64 + pA * 8);
        bfr[i] = *(const bf16x8*)(Bs + rB * 64 + pB * 8);
      }
#pragma unroll
      for (int mi = 0; mi < 4; ++mi)
#pragma unroll
        for (int ni = 0; ni < 4; ++ni)
          acc[mi][ni] = __builtin_amdgcn_mfma_f32_16x16x32_bf16(af[mi], bfr[ni], acc[mi][ni], 0, 0, 0);
    }
  }

  __syncthreads();  // K-loop LDS reads done; reuse smem as padded Pt
  __hip_bfloat16* Pt = smem;  // [128][PTL] halfs = 34 KB

  float csum[4] = {0.f, 0.f, 0.f, 0.f};
  float cmax[4] = {0.f, 0.f, 0.f, 0.f};  // clamp at 0 valid (diag of full matrix is 0)

#pragma unroll
  for (int mi = 0; mi < 4; ++mi) {
#pragma unroll
    for (int r = 0; r < 4; ++r) {
      const int rowL = wRow * 64 + mi * 16 + quad * 4 + r;
      const int row_g = rowBase + rowL;
      float ps = 0.f;
      float mx = 0.f;  // clamp at 0 valid: diag contributes sim=0 to true row max
#pragma unroll
      for (int ni = 0; ni < 4; ++ni) {
        const int colL = wCol * 64 + ni * 16 + l16;
        const int col_g = colBase + colL;
        float s = acc[mi][ni][r];
        if (row_g == col_g) s = 0.f;   // only possible on diagonal tiles
        const float p = __expf(s);     // T=1; |s|<=1 so no max-subtraction needed
        mx = fmaxf(mx, s);
        ps += p;
        csum[ni] += p;
        cmax[ni] = fmaxf(cmax[ni], s);
        Pt[rowL * PTL + colL] = __float2bfloat16(p);
      }
#pragma unroll
      for (int o = 1; o < 16; o <<= 1) {
        ps += __shfl_xor(ps, o, 64);
        mx = fmaxf(mx, __shfl_xor(mx, o, 64));
      }
      if (l16 == 0) {
        atomicAdd(lsum + (size_t)b * NN + row_g, ps);
        atomicMax(conf + (size_t)b * NN + row_g, __float_as_uint(mx));  // nonneg: uint order == float order
      }
    }
  }

  // column stats -> stripe tj rows (mirror contribution), off-diag only
  if (offdiag) {
#pragma unroll
    for (int ni = 0; ni < 4; ++ni) {
      float cs = csum[ni];
      float cm = cmax[ni];
      cs += __shfl_xor(cs, 16, 64); cm = fmaxf(cm, __shfl_xor(cm, 16, 64));
      cs += __shfl_xor(cs, 32, 64); cm = fmaxf(cm, __shfl_xor(cm, 32, 64));
      if (quad == 0) {
        const int col_g = colBase + wCol * 64 + ni * 16 + l16;
        atomicAdd(lsum + (size_t)b * NN + col_g, cs);
        atomicMax(conf + (size_t)b * NN + col_g, __float_as_uint(cm));
      }
    }
  }

  __syncthreads();
  // direct store: P[b][stripe ti][stripe tj]
  {
    const size_t pBase = ((size_t)b * NN + rowBase) * (size_t)NN + colBase;
#pragma unroll
    for (int i = 0; i < 8; ++i) {
      const int c = i * 256 + t;  // 2048 chunks of 16B
      const int row = c >> 4;
      const int ck = c & 15;
      *(uint4*)(P + pBase + (size_t)row * NN + ck * 8) = *(const uint4*)(Pt + row * PTL + ck * 8);
    }
  }

  if (offdiag) {
    __syncthreads();
    // rewrite Pt transposed from accumulators: PtT[col][row] = p (packed 4 halfs along r)
#pragma unroll
    for (int mi = 0; mi < 4; ++mi) {
#pragma unroll
      for (int ni = 0; ni < 4; ++ni) {
        const int colL = wCol * 64 + ni * 16 + l16;
        const int rbase = wRow * 64 + mi * 16 + quad * 4;
        union { ushort4 u; __hip_bfloat16 h[4]; } pk;
#pragma unroll
        for (int r = 0; r < 4; ++r) pk.h[r] = __float2bfloat16(__expf(acc[mi][ni][r]));  // ti!=tj: no diag
        *(ushort4*)(Pt + colL * PTL + rbase) = pk.u;
      }
    }
    __syncthreads();
    // mirrored store: P[b][stripe tj][stripe ti]
    const size_t pBase = ((size_t)b * NN + colBase) * (size_t)NN + rowBase;
#pragma unroll
    for (int i = 0; i < 8; ++i) {
      const int c = i * 256 + t;
      const int row = c >> 4;
      const int ck = c & 15;
      *(uint4*)(P + pBase + (size_t)row * NN + ck * 8) = *(const uint4*)(Pt + row * PTL + ck * 8);
    }
  }
}

// ---------------- GEMM2: O = P·V ; pipelined dbuf LDS; epilogue normalize + blend ----------------
__global__ __launch_bounds__(256) void gemm_pv_kernel(
    const __hip_bfloat16* __restrict__ P,    // [B][N][N]
    const __hip_bfloat16* __restrict__ Vt,   // [B][D][N]
    const float* __restrict__ lsum,
    const float* __restrict__ conf,
    const float* __restrict__ F,             // [B][N][D] fp32
    float* __restrict__ Out) {
  __shared__ __hip_bfloat16 smem[4 * 128 * 64];  // 64 KB

  const int d = blockIdx.x;                 // 0..767
  const int work = (d & 7) * 96 + (d >> 3);  // XCD k <- batch k (Vt batch 3 MB fits XCD L2)
  const int colBase = (work % 6) * 128;        // over D
  const int rowBase = ((work / 6) & 15) * 128; // over N
  const int b = work / 96;

  const int t = threadIdx.x;
  const int lane = t & 63;
  const int wave = t >> 6;
  const int wRow = wave >> 1;
  const int wCol = wave & 1;
  const int quad = lane >> 4;
  const int l16 = lane & 15;

  const __hip_bfloat16* Abase = P + (size_t)b * NN * NN + (size_t)rowBase * NN;
  const __hip_bfloat16* Bbase = Vt + (size_t)b * DD * NN + (size_t)colBase * NN;

  int srow[4], scol[4], sc8[4];
#pragma unroll
  for (int i = 0; i < 4; ++i) {
    const int c = i * 256 + t;
    srow[i] = c >> 3;
    const int col8 = (c & 7) ^ ((c >> 3) & 7);
    scol[i] = col8 * 8;
    sc8[i] = c * 8;
  }

  f32x4 acc[4][4];
#pragma unroll
  for (int i = 0; i < 4; ++i)
#pragma unroll
    for (int j = 0; j < 4; ++j) acc[i][j] = (f32x4){0.f, 0.f, 0.f, 0.f};

  {
    __hip_bfloat16* As = smem;
    __hip_bfloat16* Bs = smem + 128 * 64;
#pragma unroll
    for (int i = 0; i < 4; ++i) {
      gload_lds16(Abase + (size_t)srow[i] * NN + scol[i], As + sc8[i]);
      gload_lds16(Bbase + (size_t)srow[i] * NN + scol[i], Bs + sc8[i]);
    }
  }

  constexpr int NK = NN / 64;  // 32
  for (int kk = 0; kk < NK; ++kk) {
    const int cur = kk & 1;
    __syncthreads();
    if (kk + 1 < NK) {
      __hip_bfloat16* As = smem + (1 - cur) * 2 * 128 * 64;
      __hip_bfloat16* Bs = As + 128 * 64;
      const int k0 = (kk + 1) * 64;
#pragma unroll
      for (int i = 0; i < 4; ++i) {
        gload_lds16(Abase + (size_t)srow[i] * NN + (k0 + scol[i]), As + sc8[i]);
        gload_lds16(Bbase + (size_t)srow[i] * NN + (k0 + scol[i]), Bs + sc8[i]);
      }
    }
    const __hip_bfloat16* As = smem + cur * 2 * 128 * 64;
    const __hip_bfloat16* Bs = As + 128 * 64;
#pragma unroll
    for (int ks = 0; ks < 2; ++ks) {
      bf16x8 af[4], bfr[4];
#pragma unroll
      for (int i = 0; i < 4; ++i) {
        const int rA = wRow * 64 + i * 16 + l16;
        const int rB = wCol * 64 + i * 16 + l16;
        const int pA = (ks * 4 + quad) ^ (rA & 7);
        const int pB = (ks * 4 + quad) ^ (rB & 7);
        af[i]  = *(const bf16x8*)(As + rA * 64 + pA * 8);
        bfr[i] = *(const bf16x8*)(Bs + rB * 64 + pB * 8);
      }
#pragma unroll
      for (int mi = 0; mi < 4; ++mi)
#pragma unroll
        for (int ni = 0; ni < 4; ++ni)
          acc[mi][ni] = __builtin_amdgcn_mfma_f32_16x16x32_bf16(af[mi], bfr[ni], acc[mi][ni], 0, 0, 0);
    }
  }

#pragma unroll
  for (int mi = 0; mi < 4; ++mi) {
#pragma unroll
    for (int r = 0; r < 4; ++r) {
      const int row_g = rowBase + wRow * 64 + mi * 16 + quad * 4 + r;
      const float li = lsum[(size_t)b * NN + row_g];
      const float cw = conf[(size_t)b * NN + row_g];
      const float inv = 1.0f / li;   // li >= 1 (diag contributes exp(0)=1)
      const float* frow = F + ((size_t)b * NN + row_g) * DD;
      float* orow = Out + ((size_t)b * NN + row_g) * DD;
#pragma unroll
      for (int ni = 0; ni < 4; ++ni) {
        const int col_g = colBase + wCol * 64 + ni * 16 + l16;
        const float o = acc[mi][ni][r] * inv;
        orow[col_g] = cw * o + (1.f - cw) * frow[col_g];
      }
    }
  }
}

extern "C" void kernel_launch(void* const* d_in, const int* in_sizes, int n_in,
                              void* d_out, int out_size, void* d_ws, size_t ws_size,
                              hipStream_t stream) {
  const float* F = (const float*)d_in[0];   // final_features
  const float* M = (const float*)d_in[1];   // mid_features
  float* Out = (float*)d_out;

  char* ws = (char*)d_ws;
  // layout: Qn (25165824) | Vt (25165824) | P (67108864) | lsum (65536) | conf (65536)
  __hip_bfloat16* Qn = (__hip_bfloat16*)(ws);
  __hip_bfloat16* Vt = (__hip_bfloat16*)(ws + 25165824);
  __hip_bfloat16* P  = (__hip_bfloat16*)(ws + 50331648);
  float* lsum        = (float*)(ws + 117440512);
  float* conf        = (float*)(ws + 117506048);

  normalize_kernel<<<(BB * NN) / 4, 256, 0, stream>>>(M, Qn, lsum, conf);
  transpose_kernel<<<dim3(DD / 32, NN / 32, BB), dim3(32, 8), 0, stream>>>(F, Vt);
  gemm_qk_kernel<<<8 * 136, 256, 0, stream>>>(Qn, P, lsum, (unsigned*)conf);
  gemm_pv_kernel<<<768, 256, 0, stream>>>(P, Vt, lsum, conf, F, Out);
}

// Round 5
// 268.441 us; speedup vs baseline: 1.2778x; 1.0847x over previous
//
#include <hip/hip_runtime.h>
#include <hip/hip_bf16.h>

// Problem constants (setup_inputs: B=8, N=2048, D=768, fp32)
static constexpr int BB = 8;
static constexpr int NN = 2048;
static constexpr int DD = 768;

typedef __attribute__((ext_vector_type(8))) __bf16 bf16x8;
typedef __attribute__((ext_vector_type(4))) float f32x4;

__device__ __forceinline__ void gload_lds16(const __hip_bfloat16* g, __hip_bfloat16* l) {
  __builtin_amdgcn_global_load_lds(
      (const __attribute__((address_space(1))) void*)g,
      (__attribute__((address_space(3))) void*)l,
      16, 0, 0);
}

// ---------------- prep: normalize mid -> Qn bf16 (+zero lsum/conf) AND transpose F -> Vt bf16 ----------------
static constexpr int NORM_BLOCKS = (BB * NN) / 4;          // 4096
static constexpr int TRANS_BLOCKS = (DD / 32) * (NN / 32) * BB;  // 24*64*8 = 12288
__global__ void prep_kernel(const float* __restrict__ mid, __hip_bfloat16* __restrict__ Qn,
                            float* __restrict__ lsum, float* __restrict__ conf,
                            const float* __restrict__ F, __hip_bfloat16* __restrict__ Vt) {
  __shared__ __hip_bfloat16 tile[32][33];
  const int t = threadIdx.x;
  if (blockIdx.x < NORM_BLOCKS) {
    const int wave = t >> 6;
    const int lane = t & 63;
    const size_t row = (size_t)blockIdx.x * 4 + wave;
    if (lane == 0) { lsum[row] = 0.f; conf[row] = 0.f; }
    const float* src = mid + row * DD;

    float4 v[3];
    float ss = 0.f;
#pragma unroll
    for (int j = 0; j < 3; ++j) {
      v[j] = *(const float4*)(src + j * 256 + lane * 4);
      ss += v[j].x * v[j].x + v[j].y * v[j].y + v[j].z * v[j].z + v[j].w * v[j].w;
    }
#pragma unroll
    for (int o = 32; o; o >>= 1) ss += __shfl_xor(ss, o, 64);
    const float inv = 1.0f / fmaxf(sqrtf(ss), 1e-12f);

    __hip_bfloat16* dst = Qn + row * DD;
#pragma unroll
    for (int j = 0; j < 3; ++j) {
      union { ushort4 u; __hip_bfloat16 h[4]; } pk;
      pk.h[0] = __float2bfloat16(v[j].x * inv);
      pk.h[1] = __float2bfloat16(v[j].y * inv);
      pk.h[2] = __float2bfloat16(v[j].z * inv);
      pk.h[3] = __float2bfloat16(v[j].w * inv);
      *(ushort4*)(dst + j * 256 + lane * 4) = pk.u;
    }
  } else {
    const int bid = blockIdx.x - NORM_BLOCKS;
    const int bx = bid % 24;
    const int rest = bid / 24;
    const int by = rest & 63;
    const int b = rest >> 6;
    const int n0 = by * 32;
    const int d0 = bx * 32;
    const int tx = t & 31, ty = t >> 5;
#pragma unroll
    for (int i = 0; i < 4; ++i) {
      const int n = n0 + ty + i * 8;
      tile[ty + i * 8][tx] = __float2bfloat16(F[((size_t)b * NN + n) * DD + d0 + tx]);
    }
    __syncthreads();
#pragma unroll
    for (int i = 0; i < 4; ++i) {
      const int d = d0 + ty + i * 8;
      Vt[((size_t)b * DD + d) * NN + n0 + tx] = tile[tx][ty + i * 8];
    }
  }
}

// ---------------- GEMM1 (symmetric): S = Qn·Qnᵀ, upper-triangle tiles only ----------------
// Off-diag tile (i,j), j>i: both P[i,j] and P[j,i]^T built in-stats-loop (acc dies at first use);
// Pt/Mt are 128x128 XOR-chunk-swizzled (chunk ^= row&7) so both fit in 64 KB with the dbuf union.
__global__ __launch_bounds__(256) void gemm_qk_kernel(
    const __hip_bfloat16* __restrict__ Qn,
    __hip_bfloat16* __restrict__ P,
    float* __restrict__ lsum,
    unsigned* __restrict__ conf) {
  __shared__ __hip_bfloat16 smem[4 * 128 * 64];  // 64 KB: dbuf staging; epilogue: Pt(32K)+Mt(32K)

  const int d = blockIdx.x;                // 0..1087 (8 batches x 136 triangle tiles)
  const int b = d & 7;                     // XCD k <- batch k (Qn batch 3 MB fits XCD L2)
  int rem = d >> 3;                        // 0..135
  int ti = 0;
  while (rem >= 16 - ti) { rem -= 16 - ti; ++ti; }   // uniform scalar decode
  const int tj = ti + rem;                 // tj >= ti
  const int rowBase = ti * 128;
  const int colBase = tj * 128;
  const bool offdiag = (ti != tj);

  const int t = threadIdx.x;
  const int lane = t & 63;
  const int wave = t >> 6;
  const int wRow = wave >> 1;
  const int wCol = wave & 1;
  const int quad = lane >> 4;
  const int l16 = lane & 15;

  const __hip_bfloat16* Abase = Qn + ((size_t)b * NN + rowBase) * DD;
  const __hip_bfloat16* Bbase = Qn + ((size_t)b * NN + colBase) * DD;

  // staging slots (lane-contiguous dest for global_load_lds; source XOR-swizzled)
  int srow[4], scol[4], sc8[4];
#pragma unroll
  for (int i = 0; i < 4; ++i) {
    const int c = i * 256 + t;
    srow[i] = c >> 3;
    const int col8 = (c & 7) ^ ((c >> 3) & 7);
    scol[i] = col8 * 8;
    sc8[i] = c * 8;
  }

  f32x4 acc[4][4];
#pragma unroll
  for (int i = 0; i < 4; ++i)
#pragma unroll
    for (int j = 0; j < 4; ++j) acc[i][j] = (f32x4){0.f, 0.f, 0.f, 0.f};

  // prologue: stage tile 0 into buf 0
  {
    __hip_bfloat16* As = smem;
    __hip_bfloat16* Bs = smem + 128 * 64;
#pragma unroll
    for (int i = 0; i < 4; ++i) {
      gload_lds16(Abase + (size_t)srow[i] * DD + scol[i], As + sc8[i]);
      gload_lds16(Bbase + (size_t)srow[i] * DD + scol[i], Bs + sc8[i]);
    }
  }

  constexpr int NK = DD / 64;  // 12
  for (int kk = 0; kk < NK; ++kk) {
    const int cur = kk & 1;
    __syncthreads();  // buf[cur] staged; buf[1-cur] consumed
    if (kk + 1 < NK) {
      __hip_bfloat16* As = smem + (1 - cur) * 2 * 128 * 64;
      __hip_bfloat16* Bs = As + 128 * 64;
      const int k0 = (kk + 1) * 64;
#pragma unroll
      for (int i = 0; i < 4; ++i) {
        gload_lds16(Abase + (size_t)srow[i] * DD + (k0 + scol[i]), As + sc8[i]);
        gload_lds16(Bbase + (size_t)srow[i] * DD + (k0 + scol[i]), Bs + sc8[i]);
      }
    }
    const __hip_bfloat16* As = smem + cur * 2 * 128 * 64;
    const __hip_bfloat16* Bs = As + 128 * 64;
#pragma unroll
    for (int ks = 0; ks < 2; ++ks) {
      bf16x8 af[4], bfr[4];
#pragma unroll
      for (int i = 0; i < 4; ++i) {
        const int rA = wRow * 64 + i * 16 + l16;
        const int rB = wCol * 64 + i * 16 + l16;
        const int pA = (ks * 4 + quad) ^ (rA & 7);
        const int pB = (ks * 4 + quad) ^ (rB & 7);
        af[i]  = *(const bf16x8*)(As + rA * 64 + pA * 8);
        bfr[i] = *(const bf16x8*)(Bs + rB * 64 + pB * 8);
      }
#pragma unroll
      for (int mi = 0; mi < 4; ++mi)
#pragma unroll
        for (int ni = 0; ni < 4; ++ni)
          acc[mi][ni] = __builtin_amdgcn_mfma_f32_16x16x32_bf16(af[mi], bfr[ni], acc[mi][ni], 0, 0, 0);
    }
  }

  __syncthreads();  // K-loop LDS reads done; reuse smem as Pt + Mt (XOR-swizzled)
  __hip_bfloat16* Pt = smem;              // direct tile  [128][128]
  __hip_bfloat16* Mt = smem + 128 * 128;  // mirror tile  [128][128]

  float csum[4] = {0.f, 0.f, 0.f, 0.f};
  float cmax[4] = {0.f, 0.f, 0.f, 0.f};  // clamp at 0 valid (diag of full matrix is 0)

#pragma unroll
  for (int mi = 0; mi < 4; ++mi) {
    const int rbase = wRow * 64 + mi * 16 + quad * 4;
    float rs[4] = {0.f, 0.f, 0.f, 0.f};
    float rm[4] = {0.f, 0.f, 0.f, 0.f};
#pragma unroll
    for (int ni = 0; ni < 4; ++ni) {
      const int colL = wCol * 64 + ni * 16 + l16;
      const int col_g = colBase + colL;
      union { ushort4 u; __hip_bfloat16 h[4]; } pk;
#pragma unroll
      for (int r = 0; r < 4; ++r) {
        const int rowL = rbase + r;
        float s = acc[mi][ni][r];
        if (rowBase + rowL == col_g) s = 0.f;   // only possible on diagonal tiles
        const float p = __expf(s);              // T=1; |s|<=1 so no max-subtraction needed
        rm[r] = fmaxf(rm[r], s);
        rs[r] += p;
        csum[ni] += p;
        cmax[ni] = fmaxf(cmax[ni], s);
        pk.h[r] = __float2bfloat16(p);
        Pt[rowL * 128 + (((colL >> 3) ^ (rowL & 7)) << 3) + (colL & 7)] = pk.h[r];
      }
      if (offdiag) {  // mirror: Mt[colL][rbase..rbase+3] (8B-aligned: rbase%4==0, rbase&7 in {0,4})
        *(ushort4*)(Mt + colL * 128 + (((rbase >> 3) ^ (colL & 7)) << 3) + (rbase & 7)) = pk.u;
      }
    }
#pragma unroll
    for (int r = 0; r < 4; ++r) {
      float ps = rs[r], mx = rm[r];
#pragma unroll
      for (int o = 1; o < 16; o <<= 1) {
        ps += __shfl_xor(ps, o, 64);
        mx = fmaxf(mx, __shfl_xor(mx, o, 64));
      }
      if (l16 == 0) {
        const int row_g = rowBase + rbase + r;
        atomicAdd(lsum + (size_t)b * NN + row_g, ps);
        atomicMax(conf + (size_t)b * NN + row_g, __float_as_uint(mx));  // nonneg: uint order == float order
      }
    }
  }

  // column stats -> stripe tj rows (mirror contribution), off-diag only
  if (offdiag) {
#pragma unroll
    for (int ni = 0; ni < 4; ++ni) {
      float cs = csum[ni];
      float cm = cmax[ni];
      cs += __shfl_xor(cs, 16, 64); cm = fmaxf(cm, __shfl_xor(cm, 16, 64));
      cs += __shfl_xor(cs, 32, 64); cm = fmaxf(cm, __shfl_xor(cm, 32, 64));
      if (quad == 0) {
        const int col_g = colBase + wCol * 64 + ni * 16 + l16;
        atomicAdd(lsum + (size_t)b * NN + col_g, cs);
        atomicMax(conf + (size_t)b * NN + col_g, __float_as_uint(cm));
      }
    }
  }

  __syncthreads();
  // direct store: P[b][stripe ti][stripe tj]
  {
    const size_t pBase = ((size_t)b * NN + rowBase) * (size_t)NN + colBase;
#pragma unroll
    for (int i = 0; i < 8; ++i) {
      const int c = i * 256 + t;  // 2048 chunks of 16B
      const int row = c >> 4;
      const int ck = c & 15;
      *(uint4*)(P + pBase + (size_t)row * NN + ck * 8) =
          *(const uint4*)(Pt + row * 128 + ((ck ^ (row & 7)) << 3));
    }
  }
  if (offdiag) {
    // mirrored store: P[b][stripe tj][stripe ti]
    const size_t pBase = ((size_t)b * NN + colBase) * (size_t)NN + rowBase;
#pragma unroll
    for (int i = 0; i < 8; ++i) {
      const int c = i * 256 + t;
      const int row = c >> 4;
      const int ck = c & 15;
      *(uint4*)(P + pBase + (size_t)row * NN + ck * 8) =
          *(const uint4*)(Mt + row * 128 + ((ck ^ (row & 7)) << 3));
    }
  }
}

// ---------------- GEMM2: O = P·V ; pipelined dbuf LDS; epilogue normalize + blend ----------------
__global__ __launch_bounds__(256) void gemm_pv_kernel(
    const __hip_bfloat16* __restrict__ P,    // [B][N][N]
    const __hip_bfloat16* __restrict__ Vt,   // [B][D][N]
    const float* __restrict__ lsum,
    const float* __restrict__ conf,
    const float* __restrict__ F,             // [B][N][D] fp32
    float* __restrict__ Out) {
  __shared__ __hip_bfloat16 smem[4 * 128 * 64];  // 64 KB

  const int d = blockIdx.x;                 // 0..767
  const int work = (d & 7) * 96 + (d >> 3);  // XCD k <- batch k (Vt batch 3 MB fits XCD L2)
  const int colBase = (work % 6) * 128;        // over D
  const int rowBase = ((work / 6) & 15) * 128; // over N
  const int b = work / 96;

  const int t = threadIdx.x;
  const int lane = t & 63;
  const int wave = t >> 6;
  const int wRow = wave >> 1;
  const int wCol = wave & 1;
  const int quad = lane >> 4;
  const int l16 = lane & 15;

  const __hip_bfloat16* Abase = P + (size_t)b * NN * NN + (size_t)rowBase * NN;
  const __hip_bfloat16* Bbase = Vt + (size_t)b * DD * NN + (size_t)colBase * NN;

  int srow[4], scol[4], sc8[4];
#pragma unroll
  for (int i = 0; i < 4; ++i) {
    const int c = i * 256 + t;
    srow[i] = c >> 3;
    const int col8 = (c & 7) ^ ((c >> 3) & 7);
    scol[i] = col8 * 8;
    sc8[i] = c * 8;
  }

  f32x4 acc[4][4];
#pragma unroll
  for (int i = 0; i < 4; ++i)
#pragma unroll
    for (int j = 0; j < 4; ++j) acc[i][j] = (f32x4){0.f, 0.f, 0.f, 0.f};

  {
    __hip_bfloat16* As = smem;
    __hip_bfloat16* Bs = smem + 128 * 64;
#pragma unroll
    for (int i = 0; i < 4; ++i) {
      gload_lds16(Abase + (size_t)srow[i] * NN + scol[i], As + sc8[i]);
      gload_lds16(Bbase + (size_t)srow[i] * NN + scol[i], Bs + sc8[i]);
    }
  }

  constexpr int NK = NN / 64;  // 32
  for (int kk = 0; kk < NK; ++kk) {
    const int cur = kk & 1;
    __syncthreads();
    if (kk + 1 < NK) {
      __hip_bfloat16* As = smem + (1 - cur) * 2 * 128 * 64;
      __hip_bfloat16* Bs = As + 128 * 64;
      const int k0 = (kk + 1) * 64;
#pragma unroll
      for (int i = 0; i < 4; ++i) {
        gload_lds16(Abase + (size_t)srow[i] * NN + (k0 + scol[i]), As + sc8[i]);
        gload_lds16(Bbase + (size_t)srow[i] * NN + (k0 + scol[i]), Bs + sc8[i]);
      }
    }
    const __hip_bfloat16* As = smem + cur * 2 * 128 * 64;
    const __hip_bfloat16* Bs = As + 128 * 64;
#pragma unroll
    for (int ks = 0; ks < 2; ++ks) {
      bf16x8 af[4], bfr[4];
#pragma unroll
      for (int i = 0; i < 4; ++i) {
        const int rA = wRow * 64 + i * 16 + l16;
        const int rB = wCol * 64 + i * 16 + l16;
        const int pA = (ks * 4 + quad) ^ (rA & 7);
        const int pB = (ks * 4 + quad) ^ (rB & 7);
        af[i]  = *(const bf16x8*)(As + rA * 64 + pA * 8);
        bfr[i] = *(const bf16x8*)(Bs + rB * 64 + pB * 8);
      }
#pragma unroll
      for (int mi = 0; mi < 4; ++mi)
#pragma unroll
        for (int ni = 0; ni < 4; ++ni)
          acc[mi][ni] = __builtin_amdgcn_mfma_f32_16x16x32_bf16(af[mi], bfr[ni], acc[mi][ni], 0, 0, 0);
    }
  }

#pragma unroll
  for (int mi = 0; mi < 4; ++mi) {
#pragma unroll
    for (int r = 0; r < 4; ++r) {
      const int row_g = rowBase + wRow * 64 + mi * 16 + quad * 4 + r;
      const float li = lsum[(size_t)b * NN + row_g];
      const float cw = conf[(size_t)b * NN + row_g];
      const float inv = 1.0f / li;   // li >= 1 (diag contributes exp(0)=1)
      const float* frow = F + ((size_t)b * NN + row_g) * DD;
      float* orow = Out + ((size_t)b * NN + row_g) * DD;
#pragma unroll
      for (int ni = 0; ni < 4; ++ni) {
        const int col_g = colBase + wCol * 64 + ni * 16 + l16;
        const float o = acc[mi][ni][r] * inv;
        orow[col_g] = cw * o + (1.f - cw) * frow[col_g];
      }
    }
  }
}

extern "C" void kernel_launch(void* const* d_in, const int* in_sizes, int n_in,
                              void* d_out, int out_size, void* d_ws, size_t ws_size,
                              hipStream_t stream) {
  const float* F = (const float*)d_in[0];   // final_features
  const float* M = (const float*)d_in[1];   // mid_features
  float* Out = (float*)d_out;

  char* ws = (char*)d_ws;
  // layout: Qn (25165824) | Vt (25165824) | P (67108864) | lsum (65536) | conf (65536)
  __hip_bfloat16* Qn = (__hip_bfloat16*)(ws);
  __hip_bfloat16* Vt = (__hip_bfloat16*)(ws + 25165824);
  __hip_bfloat16* P  = (__hip_bfloat16*)(ws + 50331648);
  float* lsum        = (float*)(ws + 117440512);
  float* conf        = (float*)(ws + 117506048);

  prep_kernel<<<NORM_BLOCKS + TRANS_BLOCKS, 256, 0, stream>>>(M, Qn, lsum, conf, F, Vt);
  gemm_qk_kernel<<<8 * 136, 256, 0, stream>>>(Qn, P, lsum, (unsigned*)conf);
  gemm_pv_kernel<<<768, 256, 0, stream>>>(P, Vt, lsum, conf, F, Out);
}